// Round 1
// baseline (715.079 us; speedup 1.0000x reference)
//
#include <hip/hip_runtime.h>
#include <hip/hip_bf16.h>

#define BQ 16      // batches
#define NG 64      // groups
#define SQ 4096    // sequence tokens
#define CD 768     // channels
#define ROWS (BQ*NG)
#define KSP 4      // split-K factor (768 = 4 * 192)

// ---------------------------------------------------------------------------
// transpose64: dst[N x M] = src[M x N]^T, 64x64 LDS tiles
// ---------------------------------------------------------------------------
__global__ __launch_bounds__(256)
void transpose64(const float* __restrict__ src, float* __restrict__ dst,
                 int M, int N)
{
    __shared__ float t[64][65];
    const int bx = blockIdx.x * 64;
    const int by = blockIdx.y * 64;
    const int tx = threadIdx.x & 63, tw = threadIdx.x >> 6;
#pragma unroll
    for (int i = 0; i < 16; ++i) {
        const int row = i * 4 + tw;
        t[row][tx] = src[(size_t)(by + row) * N + bx + tx];
    }
    __syncthreads();
#pragma unroll
    for (int i = 0; i < 16; ++i) {
        const int row = i * 4 + tw;
        dst[(size_t)(bx + row) * M + by + tx] = t[tx][row];
    }
}

// ---------------------------------------------------------------------------
// vecmat3: three fused vec@mat precomputes (blockIdx.y selects)
//   y=0: uq  = Wq^T bk      y=1: bqk = bq @ Wk      y=2: bvo = bv @ Wo^T
// ---------------------------------------------------------------------------
__global__ __launch_bounds__(256)
void vecmat3(const float* __restrict__ Wq, const float* __restrict__ bk,
             const float* __restrict__ Wk, const float* __restrict__ bq,
             const float* __restrict__ WoT, const float* __restrict__ bv,
             float* __restrict__ uq, float* __restrict__ bqk,
             float* __restrict__ bvo)
{
    __shared__ float red[4][64];
    const float* Mm; const float* v; float* out;
    if (blockIdx.y == 0)      { Mm = Wq;  v = bk; out = uq;  }
    else if (blockIdx.y == 1) { Mm = Wk;  v = bq; out = bqk; }
    else                      { Mm = WoT; v = bv; out = bvo; }
    const int j0 = blockIdx.x * 64;
    const int jl = threadIdx.x & 63;
    const int cs = threadIdx.x >> 6;
    double a = 0.0;
    for (int c = cs; c < CD; c += 4)
        a += (double)Mm[(size_t)c * CD + j0 + jl] * (double)v[c];
    red[cs][jl] = (float)a;
    __syncthreads();
    if (cs == 0) out[j0 + jl] = red[0][jl] + red[1][jl] + red[2][jl] + red[3][jl];
}

// ---------------------------------------------------------------------------
// delta_q: delta[r] = query[r,:].uq + bq.bk  (fp64)
// ---------------------------------------------------------------------------
__global__ __launch_bounds__(256)
void delta_q(const float* __restrict__ query, const float* __restrict__ uq,
             const float* __restrict__ bq, const float* __restrict__ bk,
             double* __restrict__ delta)
{
    const int r    = blockIdx.x * 4 + (threadIdx.x >> 6);
    const int lane = threadIdx.x & 63;
    double a = 0.0, b = 0.0;
    for (int c = lane; c < CD; c += 64) {
        a += (double)query[(size_t)r * CD + c] * (double)uq[c];
        b += (double)bq[c] * (double)bk[c];
    }
    a += b;
    for (int off = 32; off; off >>= 1) a += __shfl_down(a, off, 64);
    if (lane == 0) delta[r] = a;
}

// ---------------------------------------------------------------------------
// gemm_core: 256-thread 64x64 tile, K=192 per call (3 chunks of 64),
// 4x4 per lane. AT is A TRANSPOSED [768][lda] (staging = direct copy).
// LDS pad 72 -> all fragment reads and staging stores <=2-way (free).
// fp32 per-64-chunk partials folded into fp64 (proven score-path recipe).
// Writes fp32 partial tile into Pz (row stride CD).
// ---------------------------------------------------------------------------
__device__ __forceinline__
void gemm_core(const float* __restrict__ AT, int lda,
               const float* __restrict__ B,  int ldb,
               float* __restrict__ Pz, int r0, int c0, int k0, int prow0)
{
    __shared__ float As[64][72];
    __shared__ float Bs[64][72];
    const int tid = threadIdx.x;
    const int c4  = tid & 15;     // staging float4 col
    const int kr  = tid >> 4;     // staging row step
    const int cg  = tid & 15;     // output col group
    const int rg  = tid >> 4;     // output row group

    float  acc[4][4]; double acc64[4][4];
#pragma unroll
    for (int i = 0; i < 4; ++i)
#pragma unroll
        for (int j = 0; j < 4; ++j) { acc[i][j] = 0.f; acc64[i][j] = 0.0; }

    for (int ch = 0; ch < 3; ++ch) {
        const int kb = k0 + ch * 64;
        if (ch) __syncthreads();
#pragma unroll
        for (int i = 0; i < 4; ++i) {
            const int row = i * 16 + kr;
            *(float4*)&As[row][4 * c4] = *(const float4*)(AT + (size_t)(kb + row) * lda + r0 + 4 * c4);
            *(float4*)&Bs[row][4 * c4] = *(const float4*)(B  + (size_t)(kb + row) * ldb + c0 + 4 * c4);
        }
        __syncthreads();
#pragma unroll 8
        for (int dd = 0; dd < 64; ++dd) {
            const float4 a = *(const float4*)&As[dd][4 * rg];
            const float4 b = *(const float4*)&Bs[dd][4 * cg];
            const float av[4] = {a.x, a.y, a.z, a.w};
            const float bv[4] = {b.x, b.y, b.z, b.w};
#pragma unroll
            for (int i = 0; i < 4; ++i)
#pragma unroll
                for (int j = 0; j < 4; ++j) acc[i][j] += av[i] * bv[j];
        }
#pragma unroll
        for (int i = 0; i < 4; ++i)
#pragma unroll
            for (int j = 0; j < 4; ++j) { acc64[i][j] += (double)acc[i][j]; acc[i][j] = 0.f; }
    }
#pragma unroll
    for (int i = 0; i < 4; ++i) {
        const int row = prow0 + 4 * rg + i;
        float4 v;
        v.x = (float)acc64[i][0]; v.y = (float)acc64[i][1];
        v.z = (float)acc64[i][2]; v.w = (float)acc64[i][3];
        *(float4*)(Pz + (size_t)row * CD + c0 + 4 * cg) = v;
    }
}

// weight GEMMs fused: by<12 -> Wqk = Wq^T@Wk; by>=12 -> Wvo = Wv^T@Wo^T
__global__ __launch_bounds__(256)
void gemm_w(const float* __restrict__ Wq, const float* __restrict__ Wk,
            const float* __restrict__ Wv, const float* __restrict__ WoT,
            float* __restrict__ P)
{
    const int by = blockIdx.y;
    float* Pz = P + (size_t)blockIdx.z * (1536 * CD);
    const float* AT; const float* Bp; int r0;
    if (by < 12) { AT = Wq; Bp = Wk;  r0 = by * 64; }
    else         { AT = Wv; Bp = WoT; r0 = (by - 12) * 64; }
    gemm_core(AT, CD, Bp, CD, Pz, r0, blockIdx.x * 64, blockIdx.z * 192, by * 64);
}

// data GEMM: out-rows M=1024, AT [768][1024]
__global__ __launch_bounds__(256)
void gemm_d(const float* __restrict__ AT, const float* __restrict__ B,
            float* __restrict__ P)
{
    float* Pz = P + (size_t)blockIdx.z * (ROWS * CD);
    const int r0 = blockIdx.y * 64;
    gemm_core(AT, ROWS, B, CD, Pz, r0, blockIdx.x * 64, blockIdx.z * 192, r0);
}

// ---------------------------------------------------------------------------
// reduce_sk: out[e] = fp64 sum of KSP partials (+ epilogue).
// mode 0: none; 1: +bias[c]; 3: invf*acc + bsc*bias2[c] + bias[c]
// ---------------------------------------------------------------------------
__global__ __launch_bounds__(256)
void reduce_sk(const float* __restrict__ P, const float* __restrict__ bias,
               const float* __restrict__ bias2, const int* __restrict__ cnt,
               float* __restrict__ out, int M, int mode)
{
    const int e = blockIdx.x * 256 + threadIdx.x;
    if (e >= M * CD) return;
    const size_t MN = (size_t)M * CD;
    double a = 0.0;
#pragma unroll
    for (int z = 0; z < KSP; ++z) a += (double)P[z * MN + e];
    float v = (float)a;
    if (mode == 1) v += bias[e % CD];
    else if (mode == 3) {
        const int r = e / CD;
        const int cv = cnt[r];
        const float invf = 1.f / ((float)cv + 1.f);   // ASSIGN_EPS = 1
        v = v * invf + ((float)cv * invf) * bias2[e % CD] + bias[e % CD];
    }
    out[e] = v;
}

// ---------------------------------------------------------------------------
// score_argmax v2: 128 threads, 64n x 128s tile, 8x8 per-lane fragments.
// A operand from pre-transposed gT [768][1024] -> linear float4 staging.
// Key tile kept NATURAL [s][dd] in LDS with XOR column swizzle
// (col4 ^= row>>3): staging is linear float4 writes (no scatter, no b32
// conflicts); column-wise b128 fragment reads hit 8 distinct bank-groups.
// Chunk t+1 prefetched into registers during compute of chunk t.
// Numerics BIT-IDENTICAL to the proven kernel: per accumulator one fma per
// dd in ascending dd order inside each 64-chunk, fp64 fold at the same
// chunk boundaries, same +delta, same strict-> / ascending-n tie-break.
// ---------------------------------------------------------------------------
struct ScoreTiles { float As[64][64]; float Bs[128][64]; };
struct ScoreRed   { double bval[128][9]; int bidx[128][9]; };
union  ScoreShared { ScoreTiles t; ScoreRed r; };

__global__ __launch_bounds__(128, 1)
void score_argmax(const float* __restrict__ gT, const float* __restrict__ key,
                  const double* __restrict__ delta, int* __restrict__ idxo)
{
    __shared__ ScoreShared sh;
    __shared__ double dl[64];
    const int tid = threadIdx.x;
    const int b   = blockIdx.y;
    const int s0  = blockIdx.x * 128;
    const int sg  = tid & 15;     // s = 8*sg + j
    const int ng  = tid >> 4;     // n = 8*ng + i   (0..7)
    const int c4  = tid & 15;     // staging float4 col
    const int t4  = tid >> 4;     // staging row sub-index (0..7)

    if (tid < 64) dl[tid] = delta[b * 64 + tid];

    float  acc[8][8]; double acc64[8][8];
#pragma unroll
    for (int i = 0; i < 8; ++i)
#pragma unroll
        for (int j = 0; j < 8; ++j) { acc[i][j] = 0.f; acc64[i][j] = 0.0; }

    float4 ra[8];    // A-tile staging regs (gT rows: 64 x 64)
    float4 rb[16];   // key-tile staging regs (128 x 64)
    const float* gTb  = gT  + (size_t)b * 64 + 4 * c4;            // + kc*ROWS per chunk
    const float* keyb = key + ((size_t)b * SQ + s0) * CD + 4 * c4; // + kc per chunk

    // prologue: load chunk 0 into registers
#pragma unroll
    for (int q = 0; q < 8; ++q)
        ra[q] = *(const float4*)(gTb + (size_t)(8 * q + t4) * ROWS);
#pragma unroll
    for (int p = 0; p < 16; ++p)
        rb[p] = *(const float4*)(keyb + (size_t)(8 * p + t4) * CD);

    for (int t = 0; t < 12; ++t) {
        __syncthreads();          // previous compute done -> LDS reusable
        // registers -> LDS (linear float4; Bs with XOR column swizzle)
#pragma unroll
        for (int q = 0; q < 8; ++q)
            *(float4*)&sh.t.As[8 * q + t4][4 * c4] = ra[q];
#pragma unroll
        for (int p = 0; p < 16; ++p)
            *(float4*)&sh.t.Bs[8 * p + t4][4 * (c4 ^ p)] = rb[p];
        __syncthreads();
        // prefetch chunk t+1 (global->regs) -- hides HBM under the FMA storm
        if (t < 11) {
            const int kc = (t + 1) * 64;
            const float* ga = gTb + (size_t)kc * ROWS;
            const float* ka = keyb + kc;
#pragma unroll
            for (int q = 0; q < 8; ++q)
                ra[q] = *(const float4*)(ga + (size_t)(8 * q + t4) * ROWS);
#pragma unroll
            for (int p = 0; p < 16; ++p)
                rb[p] = *(const float4*)(ka + (size_t)(8 * p + t4) * CD);
        }
        // compute chunk t: 64 dd, 8x8 outer product per lane
#pragma unroll 4
        for (int ddq = 0; ddq < 16; ++ddq) {
            float4 kf[8];
            const int xc = ((ddq ^ sg) & 15) << 2;   // un-swizzle: global col 4*ddq
#pragma unroll
            for (int j = 0; j < 8; ++j)
                kf[j] = *(const float4*)&sh.t.Bs[8 * sg + j][xc];
#pragma unroll
            for (int d = 0; d < 4; ++d) {
                const float4 a0 = *(const float4*)&sh.t.As[4 * ddq + d][8 * ng];
                const float4 a1 = *(const float4*)&sh.t.As[4 * ddq + d][8 * ng + 4];
                const float av[8] = { a0.x, a0.y, a0.z, a0.w, a1.x, a1.y, a1.z, a1.w };
#pragma unroll
                for (int j = 0; j < 8; ++j) {
                    const float kd = (d == 0) ? kf[j].x : (d == 1) ? kf[j].y
                                   : (d == 2) ? kf[j].z : kf[j].w;
#pragma unroll
                    for (int i = 0; i < 8; ++i) acc[i][j] += av[i] * kd;
                }
            }
        }
        // fold fp32 chunk partial into fp64 (same boundaries as proven kernel)
#pragma unroll
        for (int i = 0; i < 8; ++i)
#pragma unroll
            for (int j = 0; j < 8; ++j) { acc64[i][j] += (double)acc[i][j]; acc[i][j] = 0.f; }
    }

    // per-lane argmax over this lane's 8 n values (strict >, ascending i)
    double bv[8]; int bn[8];
#pragma unroll
    for (int j = 0; j < 8; ++j) {
        bv[j] = acc64[0][j] + dl[8 * ng + 0]; bn[j] = 8 * ng;
#pragma unroll
        for (int i = 1; i < 8; ++i) {
            const double v = acc64[i][j] + dl[8 * ng + i];
            if (v > bv[j]) { bv[j] = v; bn[j] = 8 * ng + i; }
        }
    }
    __syncthreads();
#pragma unroll
    for (int j = 0; j < 8; ++j) {
        sh.r.bval[8 * sg + j][ng] = bv[j];
        sh.r.bidx[8 * sg + j][ng] = bn[j];
    }
    __syncthreads();
    {
        const int s = tid;        // 0..127 -> one s each
        double best = sh.r.bval[s][0]; int bi = sh.r.bidx[s][0];
#pragma unroll
        for (int k = 1; k < 8; ++k) {
            const double v = sh.r.bval[s][k];
            if (v > best) { best = v; bi = sh.r.bidx[s][k]; }
        }
        idxo[b * SQ + s0 + s] = bi;
    }
}

// ---------------------------------------------------------------------------
// gather_ksum (proven R3 kernel)
// ---------------------------------------------------------------------------
__global__ __launch_bounds__(256)
void gather_ksum(const float* __restrict__ key, const int* __restrict__ idx,
                 float* __restrict__ Ksum, int* __restrict__ cnt)
{
    __shared__ int slist[SQ];
    __shared__ int scount;
    const int n   = blockIdx.x;
    const int b   = blockIdx.y;
    const int tid = threadIdx.x;
    if (tid == 0) scount = 0;
    __syncthreads();

    const int* ib = idx + b * SQ;
#pragma unroll
    for (int p = 0; p < SQ / 256; ++p) {
        const int s = p * 256 + tid;
        if (ib[s] == n) {
            const int pos = atomicAdd(&scount, 1);
            slist[pos] = s;
        }
    }
    __syncthreads();
    const int m = scount;

    double a0 = 0.0, a1 = 0.0, a2 = 0.0;
    const float* kb = key + (size_t)b * SQ * CD;
    const int c1 = tid + 256, c2 = tid + 512;

    int r = 0;
    for (; r + 4 <= m; r += 4) {
        const float* p0 = kb + (size_t)slist[r]     * CD;
        const float* p1 = kb + (size_t)slist[r + 1] * CD;
        const float* p2 = kb + (size_t)slist[r + 2] * CD;
        const float* p3 = kb + (size_t)slist[r + 3] * CD;
        a0 += (double)p0[tid] + (double)p1[tid] + (double)p2[tid] + (double)p3[tid];
        a1 += (double)p0[c1] + (double)p1[c1] + (double)p2[c1] + (double)p3[c1];
        a2 += (double)p0[c2] + (double)p1[c2] + (double)p2[c2] + (double)p3[c2];
    }
    for (; r < m; ++r) {
        const float* p0 = kb + (size_t)slist[r] * CD;
        a0 += (double)p0[tid]; a1 += (double)p0[c1]; a2 += (double)p0[c2];
    }

    float* out = Ksum + (size_t)(b * 64 + n) * CD;
    out[tid] = (float)a0; out[c1] = (float)a1; out[c2] = (float)a2;
    if (tid == 0) cnt[b * 64 + n] = m;
}

// ---------------------------------------------------------------------------
extern "C" void kernel_launch(void* const* d_in, const int* in_sizes, int n_in,
                              void* d_out, int out_size, void* d_ws, size_t ws_size,
                              hipStream_t stream)
{
    const float* query = (const float*)d_in[0];
    const float* key   = (const float*)d_in[1];
    const float* Wq    = (const float*)d_in[2];
    const float* bq    = (const float*)d_in[3];
    const float* Wk    = (const float*)d_in[4];
    const float* bk    = (const float*)d_in[5];
    const float* Wv    = (const float*)d_in[6];
    const float* bv    = (const float*)d_in[7];
    const float* Wo    = (const float*)d_in[8];
    const float* bo    = (const float*)d_in[9];

    char* ws = (char*)d_ws;
    const size_t MB = 1 << 20;
    int*    cnt   = (int*)   (ws + 0);               //   4 KB
    double* delta = (double*)(ws + 4096);            //   8 KB
    float*  uq    = (float*) (ws + 16384);           //   3 KB
    float*  bqk   = (float*) (ws + 19456);           //   3 KB
    float*  bvo   = (float*) (ws + 22528);           //   3 KB
    int*    idx   = (int*)   (ws + 32768);           // 256 KB
    float*  qT    = (float*) (ws + 1 * MB);          //   3 MB  [768][1024]
    float*  WoT   = (float*) (ws + 4 * MB);          // 2.25 MB [768][768]
    float*  Wqk   = (float*) (ws + 7 * MB);          // 2.25 MB (contiguous with Wvo)
    float*  Wvo   = Wqk + 768 * 768;                 // 2.25 MB
    float*  g     = (float*) (ws + 12 * MB);         //   3 MB  [1024][768]
    float*  Ksum  = (float*) (ws + 15 * MB);         //   3 MB
    float*  KsumT = (float*) (ws + 18 * MB);         //   3 MB  [768][1024]
    float*  P     = (float*) (ws + 21 * MB);         //  19 MB  partials

    // weight precomputes
    transpose64<<<dim3(12, 12), 256, 0, stream>>>(Wo, WoT, CD, CD);
    transpose64<<<dim3(12, 16), 256, 0, stream>>>(query, qT, ROWS, CD);
    vecmat3<<<dim3(12, 3), 256, 0, stream>>>(Wq, bk, Wk, bq, WoT, bv, uq, bqk, bvo);
    delta_q<<<ROWS / 4, 256, 0, stream>>>(query, uq, bq, bk, delta);
    // [Wqk ; Wvo] = [Wq^T@Wk ; Wv^T@Wo^T]
    gemm_w<<<dim3(12, 24, KSP), 256, 0, stream>>>(Wq, Wk, Wv, WoT, P);
    reduce_sk<<<(1536 * CD) / 256, 256, 0, stream>>>(P, nullptr, nullptr, nullptr, Wqk, 1536, 0);
    // g = query @ Wqk + bqk
    gemm_d<<<dim3(12, 16, KSP), 256, 0, stream>>>(qT, Wqk, P);
    reduce_sk<<<(ROWS * CD) / 256, 256, 0, stream>>>(P, bqk, nullptr, nullptr, g, ROWS, 1);
    // gT = g^T [768][1024] -- reuses qT space (qT is dead after the gemm above)
    float* gT = qT;
    transpose64<<<dim3(12, 16), 256, 0, stream>>>(g, gT, ROWS, CD);
    // argmax assignment (v2: 128 threads, 8x8 frags, swizzled natural key tile)
    score_argmax<<<dim3(SQ / 128, BQ), 128, 0, stream>>>(gT, key, delta, idx);
    // Ksum / cnt
    gather_ksum<<<dim3(NG, BQ), 256, 0, stream>>>(key, idx, Ksum, cnt);
    transpose64<<<dim3(12, 16), 256, 0, stream>>>(Ksum, KsumT, ROWS, CD);
    // out = invf*(Ksum @ Wvo) + bsc*bvo + bo
    gemm_d<<<dim3(12, 16, KSP), 256, 0, stream>>>(KsumT, Wvo, P);
    reduce_sk<<<(ROWS * CD) / 256, 256, 0, stream>>>(P, bo, bvo, cnt, (float*)d_out, ROWS, 3);
}

// Round 2
// 672.590 us; speedup vs baseline: 1.0632x; 1.0632x over previous
//
#include <hip/hip_runtime.h>
#include <hip/hip_bf16.h>

#define BQ 16      // batches
#define NG 64      // groups
#define SQ 4096    // sequence tokens
#define CD 768     // channels
#define ROWS (BQ*NG)
#define KSP 4      // split-K factor (768 = 4 * 192)

// ---------------------------------------------------------------------------
// transpose64: dst[N x M] = src[M x N]^T, 64x64 LDS tiles
// ---------------------------------------------------------------------------
__global__ __launch_bounds__(256)
void transpose64(const float* __restrict__ src, float* __restrict__ dst,
                 int M, int N)
{
    __shared__ float t[64][65];
    const int bx = blockIdx.x * 64;
    const int by = blockIdx.y * 64;
    const int tx = threadIdx.x & 63, tw = threadIdx.x >> 6;
#pragma unroll
    for (int i = 0; i < 16; ++i) {
        const int row = i * 4 + tw;
        t[row][tx] = src[(size_t)(by + row) * N + bx + tx];
    }
    __syncthreads();
#pragma unroll
    for (int i = 0; i < 16; ++i) {
        const int row = i * 4 + tw;
        dst[(size_t)(bx + row) * M + by + tx] = t[tx][row];
    }
}

// ---------------------------------------------------------------------------
// vecmat3: three fused vec@mat precomputes (blockIdx.y selects)
//   y=0: uq  = Wq^T bk      y=1: bqk = bq @ Wk      y=2: bvo = bv @ Wo^T
// ---------------------------------------------------------------------------
__global__ __launch_bounds__(256)
void vecmat3(const float* __restrict__ Wq, const float* __restrict__ bk,
             const float* __restrict__ Wk, const float* __restrict__ bq,
             const float* __restrict__ WoT, const float* __restrict__ bv,
             float* __restrict__ uq, float* __restrict__ bqk,
             float* __restrict__ bvo)
{
    __shared__ float red[4][64];
    const float* Mm; const float* v; float* out;
    if (blockIdx.y == 0)      { Mm = Wq;  v = bk; out = uq;  }
    else if (blockIdx.y == 1) { Mm = Wk;  v = bq; out = bqk; }
    else                      { Mm = WoT; v = bv; out = bvo; }
    const int j0 = blockIdx.x * 64;
    const int jl = threadIdx.x & 63;
    const int cs = threadIdx.x >> 6;
    double a = 0.0;
    for (int c = cs; c < CD; c += 4)
        a += (double)Mm[(size_t)c * CD + j0 + jl] * (double)v[c];
    red[cs][jl] = (float)a;
    __syncthreads();
    if (cs == 0) out[j0 + jl] = red[0][jl] + red[1][jl] + red[2][jl] + red[3][jl];
}

// ---------------------------------------------------------------------------
// delta_q: delta[r] = query[r,:].uq + bq.bk  (fp64)
// ---------------------------------------------------------------------------
__global__ __launch_bounds__(256)
void delta_q(const float* __restrict__ query, const float* __restrict__ uq,
             const float* __restrict__ bq, const float* __restrict__ bk,
             double* __restrict__ delta)
{
    const int r    = blockIdx.x * 4 + (threadIdx.x >> 6);
    const int lane = threadIdx.x & 63;
    double a = 0.0, b = 0.0;
    for (int c = lane; c < CD; c += 64) {
        a += (double)query[(size_t)r * CD + c] * (double)uq[c];
        b += (double)bq[c] * (double)bk[c];
    }
    a += b;
    for (int off = 32; off; off >>= 1) a += __shfl_down(a, off, 64);
    if (lane == 0) delta[r] = a;
}

// ---------------------------------------------------------------------------
// gemm_core: 256-thread 64x64 tile, K=192 per call (3 chunks of 64),
// 4x4 per lane. AT is A TRANSPOSED [768][lda] (staging = direct copy).
// LDS pad 72 -> all fragment reads and staging stores <=2-way (free).
// fp32 per-64-chunk partials folded into fp64 (proven score-path recipe).
// Writes fp32 partial tile into Pz (row stride CD).
// ---------------------------------------------------------------------------
__device__ __forceinline__
void gemm_core(const float* __restrict__ AT, int lda,
               const float* __restrict__ B,  int ldb,
               float* __restrict__ Pz, int r0, int c0, int k0, int prow0)
{
    __shared__ float As[64][72];
    __shared__ float Bs[64][72];
    const int tid = threadIdx.x;
    const int c4  = tid & 15;     // staging float4 col
    const int kr  = tid >> 4;     // staging row step
    const int cg  = tid & 15;     // output col group
    const int rg  = tid >> 4;     // output row group

    float  acc[4][4]; double acc64[4][4];
#pragma unroll
    for (int i = 0; i < 4; ++i)
#pragma unroll
        for (int j = 0; j < 4; ++j) { acc[i][j] = 0.f; acc64[i][j] = 0.0; }

    for (int ch = 0; ch < 3; ++ch) {
        const int kb = k0 + ch * 64;
        if (ch) __syncthreads();
#pragma unroll
        for (int i = 0; i < 4; ++i) {
            const int row = i * 16 + kr;
            *(float4*)&As[row][4 * c4] = *(const float4*)(AT + (size_t)(kb + row) * lda + r0 + 4 * c4);
            *(float4*)&Bs[row][4 * c4] = *(const float4*)(B  + (size_t)(kb + row) * ldb + c0 + 4 * c4);
        }
        __syncthreads();
#pragma unroll 8
        for (int dd = 0; dd < 64; ++dd) {
            const float4 a = *(const float4*)&As[dd][4 * rg];
            const float4 b = *(const float4*)&Bs[dd][4 * cg];
            const float av[4] = {a.x, a.y, a.z, a.w};
            const float bv[4] = {b.x, b.y, b.z, b.w};
#pragma unroll
            for (int i = 0; i < 4; ++i)
#pragma unroll
                for (int j = 0; j < 4; ++j) acc[i][j] += av[i] * bv[j];
        }
#pragma unroll
        for (int i = 0; i < 4; ++i)
#pragma unroll
            for (int j = 0; j < 4; ++j) { acc64[i][j] += (double)acc[i][j]; acc[i][j] = 0.f; }
    }
#pragma unroll
    for (int i = 0; i < 4; ++i) {
        const int row = prow0 + 4 * rg + i;
        float4 v;
        v.x = (float)acc64[i][0]; v.y = (float)acc64[i][1];
        v.z = (float)acc64[i][2]; v.w = (float)acc64[i][3];
        *(float4*)(Pz + (size_t)row * CD + c0 + 4 * cg) = v;
    }
}

// weight GEMMs fused: by<12 -> Wqk = Wq^T@Wk; by>=12 -> Wvo = Wv^T@Wo^T
__global__ __launch_bounds__(256)
void gemm_w(const float* __restrict__ Wq, const float* __restrict__ Wk,
            const float* __restrict__ Wv, const float* __restrict__ WoT,
            float* __restrict__ P)
{
    const int by = blockIdx.y;
    float* Pz = P + (size_t)blockIdx.z * (1536 * CD);
    const float* AT; const float* Bp; int r0;
    if (by < 12) { AT = Wq; Bp = Wk;  r0 = by * 64; }
    else         { AT = Wv; Bp = WoT; r0 = (by - 12) * 64; }
    gemm_core(AT, CD, Bp, CD, Pz, r0, blockIdx.x * 64, blockIdx.z * 192, by * 64);
}

// data GEMM: out-rows M=1024, AT [768][1024]
__global__ __launch_bounds__(256)
void gemm_d(const float* __restrict__ AT, const float* __restrict__ B,
            float* __restrict__ P)
{
    float* Pz = P + (size_t)blockIdx.z * (ROWS * CD);
    const int r0 = blockIdx.y * 64;
    gemm_core(AT, ROWS, B, CD, Pz, r0, blockIdx.x * 64, blockIdx.z * 192, r0);
}

// ---------------------------------------------------------------------------
// reduce_sk: out[e] = fp64 sum of KSP partials (+ epilogue).
// mode 0: none; 1: +bias[c]; 3: invf*acc + bsc*bias2[c] + bias[c]
// ---------------------------------------------------------------------------
__global__ __launch_bounds__(256)
void reduce_sk(const float* __restrict__ P, const float* __restrict__ bias,
               const float* __restrict__ bias2, const int* __restrict__ cnt,
               float* __restrict__ out, int M, int mode)
{
    const int e = blockIdx.x * 256 + threadIdx.x;
    if (e >= M * CD) return;
    const size_t MN = (size_t)M * CD;
    double a = 0.0;
#pragma unroll
    for (int z = 0; z < KSP; ++z) a += (double)P[z * MN + e];
    float v = (float)a;
    if (mode == 1) v += bias[e % CD];
    else if (mode == 3) {
        const int r = e / CD;
        const int cv = cnt[r];
        const float invf = 1.f / ((float)cv + 1.f);   // ASSIGN_EPS = 1
        v = v * invf + ((float)cv * invf) * bias2[e % CD] + bias[e % CD];
    }
    out[e] = v;
}

// ---------------------------------------------------------------------------
// score_argmax v3: 128 threads, 64n x 128s tile, 8x8 per-lane fragments.
// NO persistent prefetch registers (v2's spill source): staging goes
// global -> 8 transient float4 -> LDS in 3 small batches, so peak register
// demand ~245 fits the 256-reg cap from __launch_bounds__(128,2).
// LDS 48 KB single-buffer -> 2 blocks/CU co-resident; block-local barrier
// stalls are covered by the other block's compute (implicit overlap).
// Bs stored [s][k] with write-side XOR swizzle col4^=(row>>3): global reads
// linear/coalesced, LDS writes contiguous, fragment reads 2-way (free).
// A-tile reads are 4-address broadcasts (free).
// Numerics BIT-IDENTICAL to the proven kernel: per accumulator one fma per
// dd in ascending order inside each 64-chunk, fp64 fold at the same 12
// chunk boundaries, same fp64 +delta, same strict-> / smallest-n tie-break.
// ---------------------------------------------------------------------------
struct ScoreTiles { float As[64][64]; float Bs[128][64]; };
struct ScoreRed   { double bval[128][9]; int bidx[128][9]; };
union  ScoreShared { ScoreTiles t; ScoreRed r; };

__global__ __launch_bounds__(128, 2)
void score_argmax(const float* __restrict__ gT, const float* __restrict__ key,
                  const double* __restrict__ delta, int* __restrict__ idxo)
{
    __shared__ ScoreShared sh;
    const int tid = threadIdx.x;
    const int b   = blockIdx.y;
    const int s0  = blockIdx.x * 128;
    const int sg  = tid & 15;     // s-group: s = 8*sg + j
    const int ng  = tid >> 4;     // n-group: n = 8*ng + i (0..7)
    const int w   = tid >> 6;     // wave id (0,1)
    const int l   = tid & 63;     // lane in wave
    const int lr  = l >> 4;       // staging sub-row (0..3)
    const int c4  = l & 15;       // staging float4 col

    float  acc[8][8]; double acc64[8][8];
#pragma unroll
    for (int i = 0; i < 8; ++i)
#pragma unroll
        for (int j = 0; j < 8; ++j) { acc[i][j] = 0.f; acc64[i][j] = 0.0; }

    const float* keyb = key + ((size_t)b * SQ + s0) * CD;

    for (int t = 0; t < 12; ++t) {
        const int kb = t * 64;
        __syncthreads();              // previous compute done -> LDS reusable
        // ---- stage Bs: 128 rows x 64 k, per wave 64 rows in 2 batches of 8
#pragma unroll
        for (int half = 0; half < 2; ++half) {
            float4 r[8];
#pragma unroll
            for (int it = 0; it < 8; ++it) {
                const int row = w * 64 + (half * 8 + it) * 4 + lr;
                r[it] = *(const float4*)(keyb + (size_t)row * CD + kb + 4 * c4);
            }
#pragma unroll
            for (int it = 0; it < 8; ++it) {
                const int row = w * 64 + (half * 8 + it) * 4 + lr;
                *(float4*)&sh.t.Bs[row][4 * (c4 ^ (row >> 3))] = r[it];
            }
        }
        // ---- stage As: 64 k-rows x 64 n (linear), per wave 32 rows
        {
            float4 r[8];
#pragma unroll
            for (int it = 0; it < 8; ++it) {
                const int row = w * 32 + it * 4 + lr;
                r[it] = *(const float4*)(gT + (size_t)(kb + row) * ROWS + b * 64 + 4 * c4);
            }
#pragma unroll
            for (int it = 0; it < 8; ++it) {
                const int row = w * 32 + it * 4 + lr;
                *(float4*)&sh.t.As[row][4 * c4] = r[it];
            }
        }
        __syncthreads();
        // ---- compute chunk t: dd = 4*ddq + d ascending 0..63
#pragma unroll 2
        for (int ddq = 0; ddq < 16; ++ddq) {
            float4 kf[8];
            const int xc = ((ddq ^ sg) & 15) << 2;   // un-swizzle col
#pragma unroll
            for (int j = 0; j < 8; ++j)
                kf[j] = *(const float4*)&sh.t.Bs[8 * sg + j][xc];
#pragma unroll
            for (int d = 0; d < 4; ++d) {
                const float4 a0 = *(const float4*)&sh.t.As[4 * ddq + d][8 * ng];
                const float4 a1 = *(const float4*)&sh.t.As[4 * ddq + d][8 * ng + 4];
                const float av[8] = { a0.x, a0.y, a0.z, a0.w, a1.x, a1.y, a1.z, a1.w };
#pragma unroll
                for (int j = 0; j < 8; ++j) {
                    const float kd = (d == 0) ? kf[j].x : (d == 1) ? kf[j].y
                                   : (d == 2) ? kf[j].z : kf[j].w;
#pragma unroll
                    for (int i = 0; i < 8; ++i) acc[i][j] += av[i] * kd;
                }
            }
        }
        // ---- fold fp32 chunk partial into fp64 (same boundaries as proven)
#pragma unroll
        for (int i = 0; i < 8; ++i)
#pragma unroll
            for (int j = 0; j < 8; ++j) { acc64[i][j] += (double)acc[i][j]; acc[i][j] = 0.f; }
    }

    // delta straight from global (fp64, 16-lane uniform -> cache broadcast)
    double dl[8];
#pragma unroll
    for (int i = 0; i < 8; ++i) dl[i] = delta[b * 64 + 8 * ng + i];

    // per-lane argmax over this lane's 8 n values (strict >, ascending i)
    double bv[8]; int bn[8];
#pragma unroll
    for (int j = 0; j < 8; ++j) {
        bv[j] = acc64[0][j] + dl[0]; bn[j] = 8 * ng;
#pragma unroll
        for (int i = 1; i < 8; ++i) {
            const double v = acc64[i][j] + dl[i];
            if (v > bv[j]) { bv[j] = v; bn[j] = 8 * ng + i; }
        }
    }
    __syncthreads();                 // all compute/LDS-reads done -> reuse as red
#pragma unroll
    for (int j = 0; j < 8; ++j) {
        sh.r.bval[8 * sg + j][ng] = bv[j];
        sh.r.bidx[8 * sg + j][ng] = bn[j];
    }
    __syncthreads();
    {
        const int s = tid;           // 0..127 -> one s each
        double best = sh.r.bval[s][0]; int bi = sh.r.bidx[s][0];
#pragma unroll
        for (int k = 1; k < 8; ++k) {
            const double v = sh.r.bval[s][k];
            if (v > best) { best = v; bi = sh.r.bidx[s][k]; }
        }
        idxo[b * SQ + s0 + s] = bi;
    }
}

// ---------------------------------------------------------------------------
// gather_ksum (proven R3 kernel)
// ---------------------------------------------------------------------------
__global__ __launch_bounds__(256)
void gather_ksum(const float* __restrict__ key, const int* __restrict__ idx,
                 float* __restrict__ Ksum, int* __restrict__ cnt)
{
    __shared__ int slist[SQ];
    __shared__ int scount;
    const int n   = blockIdx.x;
    const int b   = blockIdx.y;
    const int tid = threadIdx.x;
    if (tid == 0) scount = 0;
    __syncthreads();

    const int* ib = idx + b * SQ;
#pragma unroll
    for (int p = 0; p < SQ / 256; ++p) {
        const int s = p * 256 + tid;
        if (ib[s] == n) {
            const int pos = atomicAdd(&scount, 1);
            slist[pos] = s;
        }
    }
    __syncthreads();
    const int m = scount;

    double a0 = 0.0, a1 = 0.0, a2 = 0.0;
    const float* kb = key + (size_t)b * SQ * CD;
    const int c1 = tid + 256, c2 = tid + 512;

    int r = 0;
    for (; r + 4 <= m; r += 4) {
        const float* p0 = kb + (size_t)slist[r]     * CD;
        const float* p1 = kb + (size_t)slist[r + 1] * CD;
        const float* p2 = kb + (size_t)slist[r + 2] * CD;
        const float* p3 = kb + (size_t)slist[r + 3] * CD;
        a0 += (double)p0[tid] + (double)p1[tid] + (double)p2[tid] + (double)p3[tid];
        a1 += (double)p0[c1] + (double)p1[c1] + (double)p2[c1] + (double)p3[c1];
        a2 += (double)p0[c2] + (double)p1[c2] + (double)p2[c2] + (double)p3[c2];
    }
    for (; r < m; ++r) {
        const float* p0 = kb + (size_t)slist[r] * CD;
        a0 += (double)p0[tid]; a1 += (double)p0[c1]; a2 += (double)p0[c2];
    }

    float* out = Ksum + (size_t)(b * 64 + n) * CD;
    out[tid] = (float)a0; out[c1] = (float)a1; out[c2] = (float)a2;
    if (tid == 0) cnt[b * 64 + n] = m;
}

// ---------------------------------------------------------------------------
extern "C" void kernel_launch(void* const* d_in, const int* in_sizes, int n_in,
                              void* d_out, int out_size, void* d_ws, size_t ws_size,
                              hipStream_t stream)
{
    const float* query = (const float*)d_in[0];
    const float* key   = (const float*)d_in[1];
    const float* Wq    = (const float*)d_in[2];
    const float* bq    = (const float*)d_in[3];
    const float* Wk    = (const float*)d_in[4];
    const float* bk    = (const float*)d_in[5];
    const float* Wv    = (const float*)d_in[6];
    const float* bv    = (const float*)d_in[7];
    const float* Wo    = (const float*)d_in[8];
    const float* bo    = (const float*)d_in[9];

    char* ws = (char*)d_ws;
    const size_t MB = 1 << 20;
    int*    cnt   = (int*)   (ws + 0);               //   4 KB
    double* delta = (double*)(ws + 4096);            //   8 KB
    float*  uq    = (float*) (ws + 16384);           //   3 KB
    float*  bqk   = (float*) (ws + 19456);           //   3 KB
    float*  bvo   = (float*) (ws + 22528);           //   3 KB
    int*    idx   = (int*)   (ws + 32768);           // 256 KB
    float*  qT    = (float*) (ws + 1 * MB);          //   3 MB  [768][1024]
    float*  WoT   = (float*) (ws + 4 * MB);          // 2.25 MB [768][768]
    float*  Wqk   = (float*) (ws + 7 * MB);          // 2.25 MB (contiguous with Wvo)
    float*  Wvo   = Wqk + 768 * 768;                 // 2.25 MB
    float*  g     = (float*) (ws + 12 * MB);         //   3 MB  [1024][768]
    float*  Ksum  = (float*) (ws + 15 * MB);         //   3 MB
    float*  KsumT = (float*) (ws + 18 * MB);         //   3 MB  [768][1024]
    float*  P     = (float*) (ws + 21 * MB);         //  19 MB  partials

    // weight precomputes
    transpose64<<<dim3(12, 12), 256, 0, stream>>>(Wo, WoT, CD, CD);
    transpose64<<<dim3(12, 16), 256, 0, stream>>>(query, qT, ROWS, CD);
    vecmat3<<<dim3(12, 3), 256, 0, stream>>>(Wq, bk, Wk, bq, WoT, bv, uq, bqk, bvo);
    delta_q<<<ROWS / 4, 256, 0, stream>>>(query, uq, bq, bk, delta);
    // [Wqk ; Wvo] = [Wq^T@Wk ; Wv^T@Wo^T]
    gemm_w<<<dim3(12, 24, KSP), 256, 0, stream>>>(Wq, Wk, Wv, WoT, P);
    reduce_sk<<<(1536 * CD) / 256, 256, 0, stream>>>(P, nullptr, nullptr, nullptr, Wqk, 1536, 0);
    // g = query @ Wqk + bqk
    gemm_d<<<dim3(12, 16, KSP), 256, 0, stream>>>(qT, Wqk, P);
    reduce_sk<<<(ROWS * CD) / 256, 256, 0, stream>>>(P, bqk, nullptr, nullptr, g, ROWS, 1);
    // gT = g^T [768][1024] -- reuses qT space (qT is dead after the gemm above)
    float* gT = qT;
    transpose64<<<dim3(12, 16), 256, 0, stream>>>(g, gT, ROWS, CD);
    // argmax assignment (v3: 128 threads, 8x8 frags, no prefetch regs)
    score_argmax<<<dim3(SQ / 128, BQ), 128, 0, stream>>>(gT, key, delta, idx);
    // Ksum / cnt
    gather_ksum<<<dim3(NG, BQ), 256, 0, stream>>>(key, idx, Ksum, cnt);
    transpose64<<<dim3(12, 16), 256, 0, stream>>>(Ksum, KsumT, ROWS, CD);
    // out = invf*(Ksum @ Wvo) + bsc*bvo + bo
    gemm_d<<<dim3(12, 16, KSP), 256, 0, stream>>>(KsumT, Wvo, P);
    reduce_sk<<<(ROWS * CD) / 256, 256, 0, stream>>>(P, bo, bvo, cnt, (float*)d_out, ROWS, 3);
}

// Round 3
// 643.238 us; speedup vs baseline: 1.1117x; 1.0456x over previous
//
#include <hip/hip_runtime.h>
#include <hip/hip_bf16.h>

#define BQ 16      // batches
#define NG 64      // groups
#define SQ 4096    // sequence tokens
#define CD 768     // channels
#define ROWS (BQ*NG)
#define KSP 4      // split-K factor (768 = 4 * 192)

// ---------------------------------------------------------------------------
// transpose64: dst[N x M] = src[M x N]^T, 64x64 LDS tiles
// ---------------------------------------------------------------------------
__global__ __launch_bounds__(256)
void transpose64(const float* __restrict__ src, float* __restrict__ dst,
                 int M, int N)
{
    __shared__ float t[64][65];
    const int bx = blockIdx.x * 64;
    const int by = blockIdx.y * 64;
    const int tx = threadIdx.x & 63, tw = threadIdx.x >> 6;
#pragma unroll
    for (int i = 0; i < 16; ++i) {
        const int row = i * 4 + tw;
        t[row][tx] = src[(size_t)(by + row) * N + bx + tx];
    }
    __syncthreads();
#pragma unroll
    for (int i = 0; i < 16; ++i) {
        const int row = i * 4 + tw;
        dst[(size_t)(bx + row) * M + by + tx] = t[tx][row];
    }
}

// ---------------------------------------------------------------------------
// vecmat3: three fused vec@mat precomputes (blockIdx.y selects)
//   y=0: uq  = Wq^T bk      y=1: bqk = bq @ Wk      y=2: bvo = bv @ Wo^T
// ---------------------------------------------------------------------------
__global__ __launch_bounds__(256)
void vecmat3(const float* __restrict__ Wq, const float* __restrict__ bk,
             const float* __restrict__ Wk, const float* __restrict__ bq,
             const float* __restrict__ WoT, const float* __restrict__ bv,
             float* __restrict__ uq, float* __restrict__ bqk,
             float* __restrict__ bvo)
{
    __shared__ float red[4][64];
    const float* Mm; const float* v; float* out;
    if (blockIdx.y == 0)      { Mm = Wq;  v = bk; out = uq;  }
    else if (blockIdx.y == 1) { Mm = Wk;  v = bq; out = bqk; }
    else                      { Mm = WoT; v = bv; out = bvo; }
    const int j0 = blockIdx.x * 64;
    const int jl = threadIdx.x & 63;
    const int cs = threadIdx.x >> 6;
    double a = 0.0;
    for (int c = cs; c < CD; c += 4)
        a += (double)Mm[(size_t)c * CD + j0 + jl] * (double)v[c];
    red[cs][jl] = (float)a;
    __syncthreads();
    if (cs == 0) out[j0 + jl] = red[0][jl] + red[1][jl] + red[2][jl] + red[3][jl];
}

// ---------------------------------------------------------------------------
// delta_q: delta[r] = query[r,:].uq + bq.bk  (fp64)
// ---------------------------------------------------------------------------
__global__ __launch_bounds__(256)
void delta_q(const float* __restrict__ query, const float* __restrict__ uq,
             const float* __restrict__ bq, const float* __restrict__ bk,
             double* __restrict__ delta)
{
    const int r    = blockIdx.x * 4 + (threadIdx.x >> 6);
    const int lane = threadIdx.x & 63;
    double a = 0.0, b = 0.0;
    for (int c = lane; c < CD; c += 64) {
        a += (double)query[(size_t)r * CD + c] * (double)uq[c];
        b += (double)bq[c] * (double)bk[c];
    }
    a += b;
    for (int off = 32; off; off >>= 1) a += __shfl_down(a, off, 64);
    if (lane == 0) delta[r] = a;
}

// ---------------------------------------------------------------------------
// gemm_core: 256-thread 64x64 tile, K=192 per call (3 chunks of 64),
// 4x4 per lane. AT is A TRANSPOSED [768][lda] (staging = direct copy).
// LDS pad 72 -> all fragment reads and staging stores <=2-way (free).
// fp32 per-64-chunk partials folded into fp64 (proven score-path recipe).
// Writes fp32 partial tile into Pz (row stride CD).
// ---------------------------------------------------------------------------
__device__ __forceinline__
void gemm_core(const float* __restrict__ AT, int lda,
               const float* __restrict__ B,  int ldb,
               float* __restrict__ Pz, int r0, int c0, int k0, int prow0)
{
    __shared__ float As[64][72];
    __shared__ float Bs[64][72];
    const int tid = threadIdx.x;
    const int c4  = tid & 15;     // staging float4 col
    const int kr  = tid >> 4;     // staging row step
    const int cg  = tid & 15;     // output col group
    const int rg  = tid >> 4;     // output row group

    float  acc[4][4]; double acc64[4][4];
#pragma unroll
    for (int i = 0; i < 4; ++i)
#pragma unroll
        for (int j = 0; j < 4; ++j) { acc[i][j] = 0.f; acc64[i][j] = 0.0; }

    for (int ch = 0; ch < 3; ++ch) {
        const int kb = k0 + ch * 64;
        if (ch) __syncthreads();
#pragma unroll
        for (int i = 0; i < 4; ++i) {
            const int row = i * 16 + kr;
            *(float4*)&As[row][4 * c4] = *(const float4*)(AT + (size_t)(kb + row) * lda + r0 + 4 * c4);
            *(float4*)&Bs[row][4 * c4] = *(const float4*)(B  + (size_t)(kb + row) * ldb + c0 + 4 * c4);
        }
        __syncthreads();
#pragma unroll 8
        for (int dd = 0; dd < 64; ++dd) {
            const float4 a = *(const float4*)&As[dd][4 * rg];
            const float4 b = *(const float4*)&Bs[dd][4 * cg];
            const float av[4] = {a.x, a.y, a.z, a.w};
            const float bv[4] = {b.x, b.y, b.z, b.w};
#pragma unroll
            for (int i = 0; i < 4; ++i)
#pragma unroll
                for (int j = 0; j < 4; ++j) acc[i][j] += av[i] * bv[j];
        }
#pragma unroll
        for (int i = 0; i < 4; ++i)
#pragma unroll
            for (int j = 0; j < 4; ++j) { acc64[i][j] += (double)acc[i][j]; acc[i][j] = 0.f; }
    }
#pragma unroll
    for (int i = 0; i < 4; ++i) {
        const int row = prow0 + 4 * rg + i;
        float4 v;
        v.x = (float)acc64[i][0]; v.y = (float)acc64[i][1];
        v.z = (float)acc64[i][2]; v.w = (float)acc64[i][3];
        *(float4*)(Pz + (size_t)row * CD + c0 + 4 * cg) = v;
    }
}

// weight GEMMs fused: by<12 -> Wqk = Wq^T@Wk; by>=12 -> Wvo = Wv^T@Wo^T
__global__ __launch_bounds__(256)
void gemm_w(const float* __restrict__ Wq, const float* __restrict__ Wk,
            const float* __restrict__ Wv, const float* __restrict__ WoT,
            float* __restrict__ P)
{
    const int by = blockIdx.y;
    float* Pz = P + (size_t)blockIdx.z * (1536 * CD);
    const float* AT; const float* Bp; int r0;
    if (by < 12) { AT = Wq; Bp = Wk;  r0 = by * 64; }
    else         { AT = Wv; Bp = WoT; r0 = (by - 12) * 64; }
    gemm_core(AT, CD, Bp, CD, Pz, r0, blockIdx.x * 64, blockIdx.z * 192, by * 64);
}

// data GEMM: out-rows M=1024, AT [768][1024]
__global__ __launch_bounds__(256)
void gemm_d(const float* __restrict__ AT, const float* __restrict__ B,
            float* __restrict__ P)
{
    float* Pz = P + (size_t)blockIdx.z * (ROWS * CD);
    const int r0 = blockIdx.y * 64;
    gemm_core(AT, ROWS, B, CD, Pz, r0, blockIdx.x * 64, blockIdx.z * 192, r0);
}

// ---------------------------------------------------------------------------
// reduce_sk: out[e] = fp64 sum of KSP partials (+ epilogue).
// mode 0: none; 1: +bias[c]; 3: invf*acc + bsc*bias2[c] + bias[c]
// ---------------------------------------------------------------------------
__global__ __launch_bounds__(256)
void reduce_sk(const float* __restrict__ P, const float* __restrict__ bias,
               const float* __restrict__ bias2, const int* __restrict__ cnt,
               float* __restrict__ out, int M, int mode)
{
    const int e = blockIdx.x * 256 + threadIdx.x;
    if (e >= M * CD) return;
    const size_t MN = (size_t)M * CD;
    double a = 0.0;
#pragma unroll
    for (int z = 0; z < KSP; ++z) a += (double)P[z * MN + e];
    float v = (float)a;
    if (mode == 1) v += bias[e % CD];
    else if (mode == 3) {
        const int r = e / CD;
        const int cv = cnt[r];
        const float invf = 1.f / ((float)cv + 1.f);   // ASSIGN_EPS = 1
        v = v * invf + ((float)cv * invf) * bias2[e % CD] + bias[e % CD];
    }
    out[e] = v;
}

// ---------------------------------------------------------------------------
// score_argmax v4: 256 threads, 64n x 128s tile, 4n x 8s per-lane fragments
// (the PROVEN 96-reg accumulator budget of the 161us kernel) with clean
// memory structure:
//   * A-tile staged linearly from pre-transposed gT [768][1024] (no in-kernel
//     transpose scatter).
//   * B-tile (key) kept NATURAL [s][k] with XOR swizzle col4 ^= row>>3:
//     staging writes are linear row copies; fragment reads (fixed j, 16
//     distinct rows across lanes) spread over 8 bank-groups x2 = free.
//   * B fragment reads move 256 B/wave (16 distinct float4, 4-lane
//     broadcast); A reads are 4-address broadcasts -> LDS data cycles ~2.5x
//     lower than the v1 scatter/kt scheme.
// No prefetch registers, no launch-bounds cap -> no spill (verify via
// WRITE_SIZE ~ 0.3 MB).
// Numerics BIT-IDENTICAL to the proven kernel: fp32 accumulate ascending dd
// within each 64-chunk, fp64 fold at the same 12 boundaries, fp64 delta at
// compare, strict-> / ascending-n tie-break.
// ---------------------------------------------------------------------------
struct ScoreTiles { float As[64][64]; float Bs[128][64]; };
struct ScoreRed   { double bval[128][17]; int bidx[128][17]; };
union  ScoreShared { ScoreTiles t; ScoreRed r; };

__global__ __launch_bounds__(256)
void score_argmax(const float* __restrict__ gT, const float* __restrict__ key,
                  const double* __restrict__ delta, int* __restrict__ idxo)
{
    __shared__ ScoreShared sh;
    const int tid = threadIdx.x;
    const int b   = blockIdx.y;
    const int s0  = blockIdx.x * 128;
    const int sg  = tid & 15;     // s-group: s = 8*sg + j (j=0..7)
    const int ng  = tid >> 4;     // n-group: n = 4*ng + i (i=0..3)
    const int c4  = tid & 15;     // staging float4 col
    const int t4  = tid >> 4;     // staging row sub-index (0..15)

    float  acc[4][8]; double acc64[4][8];
#pragma unroll
    for (int i = 0; i < 4; ++i)
#pragma unroll
        for (int j = 0; j < 8; ++j) { acc[i][j] = 0.f; acc64[i][j] = 0.0; }

    const float* keyb = key + ((size_t)b * SQ + s0) * CD;
    const float* gTb  = gT + (size_t)b * 64;

    for (int t = 0; t < 12; ++t) {
        const int kb = t * 64;
        __syncthreads();              // previous compute done -> LDS reusable
        // ---- stage Bs: 128 rows x 64 k; 8 rows per thread, linear writes
#pragma unroll
        for (int it = 0; it < 8; ++it) {
            const int row = it * 16 + t4;
            const float4 v = *(const float4*)(keyb + (size_t)row * CD + kb + 4 * c4);
            *(float4*)&sh.t.Bs[row][4 * ((c4 ^ (row >> 3)) & 15)] = v;
        }
        // ---- stage As: 64 k-rows x 64 n; 4 rows per thread, linear writes
#pragma unroll
        for (int it = 0; it < 4; ++it) {
            const int row = it * 16 + t4;
            const float4 v = *(const float4*)(gTb + (size_t)(kb + row) * ROWS + 4 * c4);
            *(float4*)&sh.t.As[row][4 * c4] = v;
        }
        __syncthreads();
        // ---- compute chunk t: dd = 4*ddq + d ascending 0..63
#pragma unroll 2
        for (int ddq = 0; ddq < 16; ++ddq) {
            float4 kf[8];
#pragma unroll
            for (int j = 0; j < 8; ++j)
                kf[j] = *(const float4*)&sh.t.Bs[8 * sg + j][4 * ((ddq ^ sg) & 15)];
#pragma unroll
            for (int d = 0; d < 4; ++d) {
                const float4 a = *(const float4*)&sh.t.As[4 * ddq + d][4 * ng];
                const float av[4] = { a.x, a.y, a.z, a.w };
#pragma unroll
                for (int j = 0; j < 8; ++j) {
                    const float kd = (d == 0) ? kf[j].x : (d == 1) ? kf[j].y
                                   : (d == 2) ? kf[j].z : kf[j].w;
#pragma unroll
                    for (int i = 0; i < 4; ++i) acc[i][j] += av[i] * kd;
                }
            }
        }
        // ---- fold fp32 chunk partial into fp64 (same boundaries as proven)
#pragma unroll
        for (int i = 0; i < 4; ++i)
#pragma unroll
            for (int j = 0; j < 8; ++j) { acc64[i][j] += (double)acc[i][j]; acc[i][j] = 0.f; }
    }

    // delta straight from global (fp64; 16-lane uniform -> cache broadcast)
    double dl[4];
#pragma unroll
    for (int i = 0; i < 4; ++i) dl[i] = delta[b * 64 + 4 * ng + i];

    // per-lane argmax over this lane's 4 n values (strict >, ascending i)
    double bv[8]; int bn[8];
#pragma unroll
    for (int j = 0; j < 8; ++j) {
        bv[j] = acc64[0][j] + dl[0]; bn[j] = 4 * ng;
#pragma unroll
        for (int i = 1; i < 4; ++i) {
            const double v = acc64[i][j] + dl[i];
            if (v > bv[j]) { bv[j] = v; bn[j] = 4 * ng + i; }
        }
    }
    __syncthreads();                 // compute reads done -> reuse LDS as red
#pragma unroll
    for (int j = 0; j < 8; ++j) {
        sh.r.bval[8 * sg + j][ng] = bv[j];
        sh.r.bidx[8 * sg + j][ng] = bn[j];
    }
    __syncthreads();
    if (tid < 128) {
        const int s = tid;           // 0..127 -> one s each
        double best = sh.r.bval[s][0]; int bi = sh.r.bidx[s][0];
#pragma unroll
        for (int k = 1; k < 16; ++k) {
            const double v = sh.r.bval[s][k];
            if (v > best) { best = v; bi = sh.r.bidx[s][k]; }
        }
        idxo[b * SQ + s0 + s] = bi;
    }
}

// ---------------------------------------------------------------------------
// gather_ksum (proven R3 kernel)
// ---------------------------------------------------------------------------
__global__ __launch_bounds__(256)
void gather_ksum(const float* __restrict__ key, const int* __restrict__ idx,
                 float* __restrict__ Ksum, int* __restrict__ cnt)
{
    __shared__ int slist[SQ];
    __shared__ int scount;
    const int n   = blockIdx.x;
    const int b   = blockIdx.y;
    const int tid = threadIdx.x;
    if (tid == 0) scount = 0;
    __syncthreads();

    const int* ib = idx + b * SQ;
#pragma unroll
    for (int p = 0; p < SQ / 256; ++p) {
        const int s = p * 256 + tid;
        if (ib[s] == n) {
            const int pos = atomicAdd(&scount, 1);
            slist[pos] = s;
        }
    }
    __syncthreads();
    const int m = scount;

    double a0 = 0.0, a1 = 0.0, a2 = 0.0;
    const float* kb = key + (size_t)b * SQ * CD;
    const int c1 = tid + 256, c2 = tid + 512;

    int r = 0;
    for (; r + 4 <= m; r += 4) {
        const float* p0 = kb + (size_t)slist[r]     * CD;
        const float* p1 = kb + (size_t)slist[r + 1] * CD;
        const float* p2 = kb + (size_t)slist[r + 2] * CD;
        const float* p3 = kb + (size_t)slist[r + 3] * CD;
        a0 += (double)p0[tid] + (double)p1[tid] + (double)p2[tid] + (double)p3[tid];
        a1 += (double)p0[c1] + (double)p1[c1] + (double)p2[c1] + (double)p3[c1];
        a2 += (double)p0[c2] + (double)p1[c2] + (double)p2[c2] + (double)p3[c2];
    }
    for (; r < m; ++r) {
        const float* p0 = kb + (size_t)slist[r] * CD;
        a0 += (double)p0[tid]; a1 += (double)p0[c1]; a2 += (double)p0[c2];
    }

    float* out = Ksum + (size_t)(b * 64 + n) * CD;
    out[tid] = (float)a0; out[c1] = (float)a1; out[c2] = (float)a2;
    if (tid == 0) cnt[b * 64 + n] = m;
}

// ---------------------------------------------------------------------------
extern "C" void kernel_launch(void* const* d_in, const int* in_sizes, int n_in,
                              void* d_out, int out_size, void* d_ws, size_t ws_size,
                              hipStream_t stream)
{
    const float* query = (const float*)d_in[0];
    const float* key   = (const float*)d_in[1];
    const float* Wq    = (const float*)d_in[2];
    const float* bq    = (const float*)d_in[3];
    const float* Wk    = (const float*)d_in[4];
    const float* bk    = (const float*)d_in[5];
    const float* Wv    = (const float*)d_in[6];
    const float* bv    = (const float*)d_in[7];
    const float* Wo    = (const float*)d_in[8];
    const float* bo    = (const float*)d_in[9];

    char* ws = (char*)d_ws;
    const size_t MB = 1 << 20;
    int*    cnt   = (int*)   (ws + 0);               //   4 KB
    double* delta = (double*)(ws + 4096);            //   8 KB
    float*  uq    = (float*) (ws + 16384);           //   3 KB
    float*  bqk   = (float*) (ws + 19456);           //   3 KB
    float*  bvo   = (float*) (ws + 22528);           //   3 KB
    int*    idx   = (int*)   (ws + 32768);           // 256 KB
    float*  qT    = (float*) (ws + 1 * MB);          //   3 MB  [768][1024]
    float*  WoT   = (float*) (ws + 4 * MB);          // 2.25 MB [768][768]
    float*  Wqk   = (float*) (ws + 7 * MB);          // 2.25 MB (contiguous with Wvo)
    float*  Wvo   = Wqk + 768 * 768;                 // 2.25 MB
    float*  g     = (float*) (ws + 12 * MB);         //   3 MB  [1024][768]
    float*  Ksum  = (float*) (ws + 15 * MB);         //   3 MB
    float*  KsumT = (float*) (ws + 18 * MB);         //   3 MB  [768][1024]
    float*  P     = (float*) (ws + 21 * MB);         //  19 MB  partials

    // weight precomputes
    transpose64<<<dim3(12, 12), 256, 0, stream>>>(Wo, WoT, CD, CD);
    transpose64<<<dim3(12, 16), 256, 0, stream>>>(query, qT, ROWS, CD);
    vecmat3<<<dim3(12, 3), 256, 0, stream>>>(Wq, bk, Wk, bq, WoT, bv, uq, bqk, bvo);
    delta_q<<<ROWS / 4, 256, 0, stream>>>(query, uq, bq, bk, delta);
    // [Wqk ; Wvo] = [Wq^T@Wk ; Wv^T@Wo^T]
    gemm_w<<<dim3(12, 24, KSP), 256, 0, stream>>>(Wq, Wk, Wv, WoT, P);
    reduce_sk<<<(1536 * CD) / 256, 256, 0, stream>>>(P, nullptr, nullptr, nullptr, Wqk, 1536, 0);
    // g = query @ Wqk + bqk
    gemm_d<<<dim3(12, 16, KSP), 256, 0, stream>>>(qT, Wqk, P);
    reduce_sk<<<(ROWS * CD) / 256, 256, 0, stream>>>(P, bqk, nullptr, nullptr, g, ROWS, 1);
    // gT = g^T [768][1024] -- reuses qT space (qT is dead after the gemm above)
    float* gT = qT;
    transpose64<<<dim3(12, 16), 256, 0, stream>>>(g, gT, ROWS, CD);
    // argmax assignment (v4: 256 threads, proven 4x8 frags, clean staging)
    score_argmax<<<dim3(SQ / 128, BQ), 256, 0, stream>>>(gT, key, delta, idx);
    // Ksum / cnt
    gather_ksum<<<dim3(NG, BQ), 256, 0, stream>>>(key, idx, Ksum, cnt);
    transpose64<<<dim3(12, 16), 256, 0, stream>>>(Ksum, KsumT, ROWS, CD);
    // out = invf*(Ksum @ Wvo) + bsc*bvo + bo
    gemm_d<<<dim3(12, 16, KSP), 256, 0, stream>>>(KsumT, Wvo, P);
    reduce_sk<<<(ROWS * CD) / 256, 256, 0, stream>>>(P, bo, bvo, cnt, (float*)d_out, ROWS, 3);
}